// Round 1
// baseline (15756.120 us; speedup 1.0000x reference)
//
#include <hip/hip_runtime.h>
#include <hip/hip_bf16.h>

// ---------------------------------------------------------------------------
// RSSMCore: 64-step scan (input MLP -> LN/ELU -> GRU -> posterior head ->
// categorical straight-through sample) + batched prior head.
// All GEMMs fp32 (no fp32 MFMA on CDNA4; bf16 would flip categorical argmax).
// Sampling reproduces JAX threefry2x32 (partitionable random_bits) exactly.
// ---------------------------------------------------------------------------

#define BK 32
#define LDP 68

enum { TR_NONE = 0, TR_SCALEROW = 1, TR_LNELU = 2 };

struct GemmArgs {
  const float* A; int lda; const float* B; int ldb; int K; int ksplit;
  const float* A2; int lda2; const float* B2; int ldb2; int K2;
  int N; const float* bias;
  const float* t1s; const float* t1g; const float* t1b;
  float* C; int ldc; long partStride;
};

// XLA f32 tanh rational approximation (mul/add, no contraction) ------------
__device__ inline float xla_tanh(float x) {
  float ax = fabsf(x);
  float xc = fminf(fmaxf(x, -7.90531110763549805f), 7.90531110763549805f);
  float x2 = __fmul_rn(xc, xc);
  float p = -2.76076847742355e-16f;
  p = __fadd_rn(__fmul_rn(p, x2), 2.00018790482477e-13f);
  p = __fadd_rn(__fmul_rn(p, x2), -8.60467152213735e-11f);
  p = __fadd_rn(__fmul_rn(p, x2), 5.12229709037114e-08f);
  p = __fadd_rn(__fmul_rn(p, x2), 1.48572235717979e-05f);
  p = __fadd_rn(__fmul_rn(p, x2), 6.37261928875436e-04f);
  p = __fadd_rn(__fmul_rn(p, x2), 4.89352455891786e-03f);
  float num = __fmul_rn(xc, p);
  float q = 1.19825839466702e-06f;
  q = __fadd_rn(__fmul_rn(q, x2), 1.18534705686654e-04f);
  q = __fadd_rn(__fmul_rn(q, x2), 2.26843463243900e-03f);
  q = __fadd_rn(__fmul_rn(q, x2), 4.89352518554385e-03f);
  float r = __fdiv_rn(num, q);
  return ax < 0.0004f ? x : r;
}

__device__ inline float sigm(float x) { return 1.0f / (1.0f + expf(-x)); }

// Threefry2x32 (20 rounds), matches jax/_src/prng.py ------------------------
__device__ inline void tfround(unsigned& x0, unsigned& x1, int r) {
  x0 += x1; x1 = (x1 << r) | (x1 >> (32 - r)); x1 ^= x0;
}
__device__ inline uint2 threefry(unsigned k0, unsigned k1, unsigned c0, unsigned c1) {
  unsigned ks2 = k0 ^ k1 ^ 0x1BD11BDAu;
  unsigned x0 = c0 + k0, x1 = c1 + k1;
  tfround(x0, x1, 13); tfround(x0, x1, 15); tfround(x0, x1, 26); tfround(x0, x1, 6);
  x0 += k1; x1 += ks2 + 1u;
  tfround(x0, x1, 17); tfround(x0, x1, 29); tfround(x0, x1, 16); tfround(x0, x1, 24);
  x0 += ks2; x1 += k0 + 2u;
  tfround(x0, x1, 13); tfround(x0, x1, 15); tfround(x0, x1, 26); tfround(x0, x1, 6);
  x0 += k0; x1 += k1 + 3u;
  tfround(x0, x1, 17); tfround(x0, x1, 29); tfround(x0, x1, 16); tfround(x0, x1, 24);
  x0 += k1; x1 += ks2 + 4u;
  tfround(x0, x1, 13); tfround(x0, x1, 15); tfround(x0, x1, 26); tfround(x0, x1, 6);
  x0 += ks2; x1 += k0 + 5u;
  return make_uint2(x0, x1);
}

// Tiled 64x64 fp32 GEMM core ------------------------------------------------
template <int TRA>
__device__ void gemm_tiles(float acc[4][4], float (*As)[LDP], float (*Bs)[LDP],
                           const float* A, int lda, const float* B, int ldb,
                           int kB, int kE, int mBase, int cBase, int N,
                           const float* s0, const float* g0, const float* b0) {
  const int tid = threadIdx.x;
  const int ar = tid >> 2;
  const int ak = (tid & 3) << 3;
  const int bk = tid >> 3;
  const int bc = (tid & 7) << 3;
  const int r0 = (tid >> 4) << 2;
  const int c0 = (tid & 15) << 2;

  float rowS = 1.f, rowM = 0.f, rowR = 1.f;
  if (TRA == TR_SCALEROW) rowS = s0[mBase + ar];
  else if (TRA == TR_LNELU) {
    rowM = s0[(mBase + ar) * 2];
    rowR = s0[(mBase + ar) * 2 + 1];
  }

  for (int kb = kB; kb < kE; kb += BK) {
    // stage A (transform applied per element; pad k>=kE with exact 0)
    {
      const float* Ap = A + (long)(mBase + ar) * lda + kb + ak;
      float v[8];
      if (kb + ak + 7 < kE) {
        float4 u0 = *(const float4*)(Ap);
        float4 u1 = *(const float4*)(Ap + 4);
        v[0] = u0.x; v[1] = u0.y; v[2] = u0.z; v[3] = u0.w;
        v[4] = u1.x; v[5] = u1.y; v[6] = u1.z; v[7] = u1.w;
      } else {
#pragma unroll
        for (int i = 0; i < 8; i++) v[i] = (kb + ak + i < kE) ? Ap[i] : 0.f;
      }
#pragma unroll
      for (int i = 0; i < 8; i++) {
        int k = kb + ak + i;
        float x = 0.f;
        if (k < kE) {
          x = v[i];
          if (TRA == TR_SCALEROW) {
            x *= rowS;
          } else if (TRA == TR_LNELU) {
            x = (x - rowM) * rowR * g0[k] + b0[k];
            x = x > 0.f ? x : expm1f(x);
          }
        }
        As[ak + i][ar] = x;
      }
    }
    // stage B
    {
      int k = kb + bk;
      const float* Bp = B + (long)k * ldb + cBase + bc;
      if (k < kE && cBase + bc + 7 < N) {
        float4 u0 = *(const float4*)(Bp);
        float4 u1 = *(const float4*)(Bp + 4);
        Bs[bk][bc + 0] = u0.x; Bs[bk][bc + 1] = u0.y;
        Bs[bk][bc + 2] = u0.z; Bs[bk][bc + 3] = u0.w;
        Bs[bk][bc + 4] = u1.x; Bs[bk][bc + 5] = u1.y;
        Bs[bk][bc + 6] = u1.z; Bs[bk][bc + 7] = u1.w;
      } else {
#pragma unroll
        for (int i = 0; i < 8; i++)
          Bs[bk][bc + i] = (k < kE && cBase + bc + i < N) ? Bp[i] : 0.f;
      }
    }
    __syncthreads();
#pragma unroll
    for (int kk = 0; kk < BK; kk++) {
      float4 a4 = *(const float4*)&As[kk][r0];
      float4 b4 = *(const float4*)&Bs[kk][c0];
      float av[4] = {a4.x, a4.y, a4.z, a4.w};
      float bv[4] = {b4.x, b4.y, b4.z, b4.w};
#pragma unroll
      for (int i = 0; i < 4; i++)
#pragma unroll
        for (int j = 0; j < 4; j++) acc[i][j] += av[i] * bv[j];
    }
    __syncthreads();
  }
}

template <int TRA, int TRA2>
__global__ __launch_bounds__(256) void k_gemm(GemmArgs g) {
  __shared__ float As[BK][LDP];
  __shared__ float Bs[BK][LDP];
  const int nT = blockIdx.x, ks = blockIdx.y, mT = blockIdx.z;
  const int mBase = mT * 64, cBase = nT * 64;
  float acc[4][4] = {};
  int chunk = (((g.K + g.ksplit - 1) / g.ksplit) + 31) & ~31;
  int kB = ks * chunk, kE = min(g.K, kB + chunk);
  if (kB < kE)
    gemm_tiles<TRA>(acc, As, Bs, g.A, g.lda, g.B, g.ldb, kB, kE, mBase, cBase,
                    g.N, g.t1s, g.t1g, g.t1b);
  if (g.A2) {
    int chunk2 = (((g.K2 + g.ksplit - 1) / g.ksplit) + 31) & ~31;
    int kB2 = ks * chunk2, kE2 = min(g.K2, kB2 + chunk2);
    if (kB2 < kE2)
      gemm_tiles<TRA2>(acc, As, Bs, g.A2, g.lda2, g.B2, g.ldb2, kB2, kE2, mBase,
                       cBase, g.N, nullptr, nullptr, nullptr);
  }
  const int tid = threadIdx.x;
  const int r0 = (tid >> 4) << 2, c0 = (tid & 15) << 2;
  float* Cb = g.C + (long)ks * g.partStride;
#pragma unroll
  for (int i = 0; i < 4; i++) {
    float4 v = make_float4(acc[i][0], acc[i][1], acc[i][2], acc[i][3]);
    if (ks == 0 && g.bias) {
      int c = cBase + c0;
      v.x += (c + 0 < g.N) ? g.bias[c + 0] : 0.f;
      v.y += (c + 1 < g.N) ? g.bias[c + 1] : 0.f;
      v.z += (c + 2 < g.N) ? g.bias[c + 2] : 0.f;
      v.w += (c + 3 < g.N) ? g.bias[c + 3] : 0.f;
    }
    *(float4*)&Cb[(long)(mBase + r0 + i) * g.ldc + cBase + c0] = v;
  }
}

// Sum split-K partials, emit LN row stats (mean, rstd) ----------------------
__global__ __launch_bounds__(256) void k_fin(const float* parts, int nParts,
                                             int partStride, float* dst,
                                             float* stats, int N) {
  const int r = blockIdx.x, tid = threadIdx.x;
  float s = 0.f, sq = 0.f;
  for (int c = tid; c < 1024; c += 256) {
    float v = 0.f;
    for (int p = 0; p < nParts; p++) v += parts[(long)p * partStride + r * 1024 + c];
    dst[r * 1024 + c] = v;
    if (c < N) { s += v; sq += v * v; }
  }
#pragma unroll
  for (int off = 32; off >= 1; off >>= 1) {
    s += __shfl_down(s, off);
    sq += __shfl_down(sq, off);
  }
  __shared__ float rs[4], rq[4];
  if ((tid & 63) == 0) { rs[tid >> 6] = s; rq[tid >> 6] = sq; }
  __syncthreads();
  if (tid == 0) {
    s = rs[0] + rs[1] + rs[2] + rs[3];
    sq = rq[0] + rq[1] + rq[2] + rq[3];
    float mean = s / N;
    float var = sq / N - mean * mean;
    stats[r * 2] = mean;
    stats[r * 2 + 1] = 1.0f / sqrtf(var + 1e-3f);
  }
}

// LN row stats for the prior path (4096 rows, 4 rows per block) -------------
__global__ __launch_bounds__(256) void k_prstat(const float* xp, float* stats, int N) {
  int wave = threadIdx.x >> 6, lane = threadIdx.x & 63;
  int r = blockIdx.x * 4 + wave;
  float s = 0.f, sq = 0.f;
  for (int c = lane; c < N; c += 64) {
    float v = xp[(long)r * 1024 + c];
    s += v; sq += v * v;
  }
#pragma unroll
  for (int off = 32; off >= 1; off >>= 1) {
    s += __shfl_down(s, off);
    sq += __shfl_down(sq, off);
  }
  if (lane == 0) {
    float mean = s / N, var = sq / N - mean * mean;
    stats[r * 2] = mean;
    stats[r * 2 + 1] = 1.0f / sqrtf(var + 1e-3f);
  }
}

// GRU gates: h_new = (1-u)*n + u*(h*m); writes into features[t] -------------
__global__ __launch_bounds__(256) void k_gates(const float* gi_p, const float* gh_p,
                                               const float* bi, const float* bh,
                                               const float* hprev, int ldh,
                                               const float* msk, float* hdst,
                                               float* hlast) {
  int i = blockIdx.x * 256 + threadIdx.x;  // 0..131071
  int b = i >> 11, d = i & 2047;
  const long s6 = 6144, PS = 393216;
  long o0 = (long)b * s6;
  float gir = gi_p[o0 + d] + gi_p[PS + o0 + d] + bi[d];
  float giz = gi_p[o0 + d + 2048] + gi_p[PS + o0 + d + 2048] + bi[d + 2048];
  float gin = gi_p[o0 + d + 4096] + gi_p[PS + o0 + d + 4096] + bi[d + 4096];
  float ghr = bh[d], ghz = bh[d + 2048], ghn = bh[d + 4096];
#pragma unroll
  for (int p = 0; p < 4; p++) {
    long o = (long)p * PS + o0;
    ghr += gh_p[o + d];
    ghz += gh_p[o + d + 2048];
    ghn += gh_p[o + d + 4096];
  }
  float rr = sigm(gir + ghr);
  float uu = sigm(giz + ghz);
  float nn = xla_tanh(gin + rr * ghn);
  float hm = hprev[(long)b * ldh + d] * msk[b];
  float h = (1.f - uu) * nn + uu * hm;
  hdst[(long)b * 3072 + d] = h;
  if (hlast) hlast[(long)b * 2048 + d] = h;
}

// pp assembly + JAX-exact categorical straight-through sample ---------------
__global__ __launch_bounds__(256) void k_sample(const float* parts, float* posts_t,
                                                float* samples_t, float* feat_t,
                                                float* zlast, int t) {
  int gid = blockIdx.x * 256 + threadIdx.x;  // 0..2047 => (b,s)
  int b = gid >> 5, s = gid & 5 * 0 + (gid & 31);
  uint2 kt = threefry(0u, 42u, 0u, (unsigned)t);  // fold_in(key(42), t)
  float pp[32];
#pragma unroll
  for (int j = 0; j < 32; j++) {
    int c = s * 32 + j;
    float v = 0.f;
    for (int p = 0; p < 8; p++) v += parts[(long)p * 65536 + b * 1024 + c];
    pp[j] = v;
    posts_t[b * 1024 + c] = v;
  }
  const float TINY = 1.175494350822287508e-38f;
  float best = -3.402823466e38f;
  int bidx = 0;
#pragma unroll
  for (int j = 0; j < 32; j++) {
    unsigned idx = (unsigned)(b * 1024 + s * 32 + j);
    uint2 o = threefry(kt.x, kt.y, 0u, idx);   // partitionable: counts (hi=0, lo=i)
    unsigned bits = o.x ^ o.y;
    float u = __uint_as_float((bits >> 9) | 0x3f800000u) - 1.0f;
    u = fmaxf(TINY, u + TINY);
    float gmb = -logf(-logf(u));
    float sc = pp[j] + gmb;
    if (sc > best) { best = sc; bidx = j; }
  }
#pragma unroll
  for (int j = 0; j < 32; j++) {
    float oh = (j == bidx) ? 1.0f : 0.0f;
    samples_t[b * 1024 + s * 32 + j] = oh;
    feat_t[b * 3072 + 2048 + s * 32 + j] = oh;
    if (zlast) zlast[b * 1024 + s * 32 + j] = oh;
  }
}

// resets dtype probe: 0 = 4-byte ints/floats (read dword!=0), 1 = 1-byte bool
__global__ void k_detect(const unsigned* rr, int nDwordsSafe, int* fmt) {
  __shared__ int flags;
  if (threadIdx.x == 0) flags = 0;
  __syncthreads();
  int local = 0;
  for (int i = threadIdx.x; i < nDwordsSafe; i += 256) {
    unsigned dw = rr[i];
    if (dw == 0x3f800000u) local |= 4;          // float 1.0 pattern
    else if (dw & 0xFFFFFF00u) local |= 1;      // nonzero byte off dword boundary
    else if (dw == 1u) local |= 2;
  }
  atomicOr(&flags, local);
  __syncthreads();
  if (threadIdx.x == 0) {
    int f = flags;
    *fmt = ((f & 4) == 0 && (f & 1)) ? 1 : 0;   // bool bytes vs 4-byte scalar
  }
}

__global__ void k_prep(const void* rr, const int* fmt, float* mask, int n) {
  int i = blockIdx.x * 256 + threadIdx.x;
  if (i < n) {
    bool reset;
    if (*fmt == 1) reset = ((const unsigned char*)rr)[i] != 0;
    else reset = ((const int*)rr)[i] != 0;  // covers int32 and float (bitwise) 0/1
    mask[i] = reset ? 0.0f : 1.0f;
  }
}

// ---------------------------------------------------------------------------
extern "C" void kernel_launch(void* const* d_in, const int* in_sizes, int n_in,
                              void* d_out, int out_size, void* d_ws, size_t ws_size,
                              hipStream_t stream) {
  const float* embeds = (const float*)d_in[0];
  const float* actions = (const float*)d_in[1];
  const void* resets = d_in[2];
  const float* h0 = (const float*)d_in[3];
  const float* z0 = (const float*)d_in[4];
  const float* zw = (const float*)d_in[5];
  const float* zb = (const float*)d_in[6];
  const float* aw = (const float*)d_in[7];
  const float* in_g = (const float*)d_in[8];
  const float* in_b = (const float*)d_in[9];
  const float* gwi = (const float*)d_in[10];
  const float* gwh = (const float*)d_in[11];
  const float* gbi = (const float*)d_in[12];
  const float* gbh = (const float*)d_in[13];
  const float* ph_w = (const float*)d_in[14];
  const float* ph_b = (const float*)d_in[15];
  const float* pe_w = (const float*)d_in[16];
  const float* po_g = (const float*)d_in[17];
  const float* po_b = (const float*)d_in[18];
  const float* pp_w = (const float*)d_in[19];
  const float* pp_b = (const float*)d_in[20];
  const float* prh_w = (const float*)d_in[21];
  const float* prh_b = (const float*)d_in[22];
  const float* pr_g = (const float*)d_in[23];
  const float* pr_b = (const float*)d_in[24];
  const float* prp_w = (const float*)d_in[25];
  const float* prp_b = (const float*)d_in[26];

  float* out = (float*)d_out;
  float* priors  = out;
  float* posts   = out + 4194304;
  float* samples = out + 8388608;
  float* feats   = out + 12582912;
  float* hlast   = out + 25165824;
  float* zlast   = out + 25296896;

  float* ws = (float*)d_ws;
  int*   fmt     = (int*)ws;
  float* mask    = ws + 64;
  float* stats_a = ws + 4160;
  float* stats_b = ws + 4288;
  float* xa      = ws + 4416;
  float* x2a     = ws + 69952;
  float* partA   = ws + 135488;   // 8 x [64][1024]
  float* gi_p    = ws + 659776;   // 2 x [64][6144]
  float* gh_p    = ws + 1446208;  // 4 x [64][6144]
  float* xp      = ws + 3019072;  // [4096][1024]
  float* stats_p = ws + 7213376;  // [4096][2]

  k_detect<<<1, 256, 0, stream>>>((const unsigned*)resets, 1024, fmt);
  k_prep<<<16, 256, 0, stream>>>(resets, fmt, mask, 4096);

  for (int t = 0; t < 64; t++) {
    const float* zprev = (t == 0) ? z0 : samples + (long)(t - 1) * 65536;
    const float* hprev = (t == 0) ? h0 : feats + (long)(t - 1) * 196608;
    int ldh = (t == 0) ? 2048 : 3072;
    float* feat_t = feats + (long)t * 196608;

    // xa = (z*m) @ zw + zb + a @ aw
    GemmArgs gin{};
    gin.A = zprev; gin.lda = 1024; gin.B = zw; gin.ldb = 1000; gin.K = 1024; gin.ksplit = 4;
    gin.A2 = actions + (long)t * 384; gin.lda2 = 6; gin.B2 = aw; gin.ldb2 = 1000; gin.K2 = 6;
    gin.N = 1000; gin.bias = zb; gin.t1s = mask + t * 64;
    gin.C = partA; gin.ldc = 1024; gin.partStride = 65536;
    k_gemm<TR_SCALEROW, TR_NONE><<<dim3(16, 4, 1), 256, 0, stream>>>(gin);
    k_fin<<<64, 256, 0, stream>>>(partA, 4, 65536, xa, stats_a, 1000);

    // gi = elu(ln(xa)) @ gru_wi   (LN+ELU applied during A staging)
    GemmArgs ggi{};
    ggi.A = xa; ggi.lda = 1024; ggi.B = gwi; ggi.ldb = 6144; ggi.K = 1000; ggi.ksplit = 2;
    ggi.N = 6144; ggi.t1s = stats_a; ggi.t1g = in_g; ggi.t1b = in_b;
    ggi.C = gi_p; ggi.ldc = 6144; ggi.partStride = 393216;
    k_gemm<TR_LNELU, TR_NONE><<<dim3(96, 2, 1), 256, 0, stream>>>(ggi);

    // gh = (h*m) @ gru_wh
    GemmArgs ggh{};
    ggh.A = hprev; ggh.lda = ldh; ggh.B = gwh; ggh.ldb = 6144; ggh.K = 2048; ggh.ksplit = 4;
    ggh.N = 6144; ggh.t1s = mask + t * 64;
    ggh.C = gh_p; ggh.ldc = 6144; ggh.partStride = 393216;
    k_gemm<TR_SCALEROW, TR_NONE><<<dim3(96, 4, 1), 256, 0, stream>>>(ggh);

    // gates -> h_new (into features[t]); h_last at t=63
    k_gates<<<512, 256, 0, stream>>>(gi_p, gh_p, gbi, gbh, hprev, ldh, mask + t * 64,
                                     feat_t, (t == 63) ? hlast : nullptr);

    // x2a = h_new @ ph_w + ph_b + e @ pe_w
    GemmArgs gpo{};
    gpo.A = feat_t; gpo.lda = 3072; gpo.B = ph_w; gpo.ldb = 1000; gpo.K = 2048; gpo.ksplit = 8;
    gpo.A2 = embeds + (long)t * 65536; gpo.lda2 = 1024; gpo.B2 = pe_w; gpo.ldb2 = 1000; gpo.K2 = 1024;
    gpo.N = 1000; gpo.bias = ph_b;
    gpo.C = partA; gpo.ldc = 1024; gpo.partStride = 65536;
    k_gemm<TR_NONE, TR_NONE><<<dim3(16, 8, 1), 256, 0, stream>>>(gpo);
    k_fin<<<64, 256, 0, stream>>>(partA, 8, 65536, x2a, stats_b, 1000);

    // pp = elu(ln(x2a)) @ pp_w + pp_b  (split-K partials)
    GemmArgs gpp{};
    gpp.A = x2a; gpp.lda = 1024; gpp.B = pp_w; gpp.ldb = 1024; gpp.K = 1000; gpp.ksplit = 8;
    gpp.N = 1024; gpp.bias = pp_b; gpp.t1s = stats_b; gpp.t1g = po_g; gpp.t1b = po_b;
    gpp.C = partA; gpp.ldc = 1024; gpp.partStride = 65536;
    k_gemm<TR_LNELU, TR_NONE><<<dim3(16, 8, 1), 256, 0, stream>>>(gpp);

    k_sample<<<8, 256, 0, stream>>>(partA, posts + (long)t * 65536,
                                    samples + (long)t * 65536, feat_t,
                                    (t == 63) ? zlast : nullptr, t);
  }

  // prior head (batched over all T*B rows)
  GemmArgs gp1{};
  gp1.A = feats; gp1.lda = 3072; gp1.B = prh_w; gp1.ldb = 1000; gp1.K = 2048; gp1.ksplit = 1;
  gp1.N = 1000; gp1.bias = prh_b; gp1.C = xp; gp1.ldc = 1024; gp1.partStride = 0;
  k_gemm<TR_NONE, TR_NONE><<<dim3(16, 1, 64), 256, 0, stream>>>(gp1);
  k_prstat<<<1024, 256, 0, stream>>>(xp, stats_p, 1000);
  GemmArgs gp2{};
  gp2.A = xp; gp2.lda = 1024; gp2.B = prp_w; gp2.ldb = 1024; gp2.K = 1000; gp2.ksplit = 1;
  gp2.N = 1024; gp2.bias = prp_b; gp2.t1s = stats_p; gp2.t1g = pr_g; gp2.t1b = pr_b;
  gp2.C = priors; gp2.ldc = 1024; gp2.partStride = 0;
  k_gemm<TR_LNELU, TR_NONE><<<dim3(16, 1, 64), 256, 0, stream>>>(gp2);
}